// Round 2
// baseline (176.792 us; speedup 1.0000x reference)
//
#include <hip/hip_runtime.h>
#include <hip/hip_bf16.h>

// ---------- helpers ----------
__device__ inline float wave_sum(float v) {
#pragma unroll
    for (int off = 32; off > 0; off >>= 1) v += __shfl_down(v, off, 64);
    return v;
}

// ---------- Kernel A1: feat group-norm partial sums ----------
// feat: (4,64,256,256). 16 groups of 4 channels -> each (b,g) is a contiguous
// 262144-float range. grid = 64 groups * 16 chunks = 1024 blocks, 256 thr.
__global__ __launch_bounds__(256) void feat_stats_partial(
    const float* __restrict__ feat, float* __restrict__ partials) {
    int blk = blockIdx.x;
    int grp = blk >> 4;     // b*16+g, 0..63
    int chunk = blk & 15;
    const float4* base = (const float4*)(feat + (size_t)grp * 262144 + (size_t)chunk * 16384);
    int tid = threadIdx.x;
    float s = 0.f, sq = 0.f;
#pragma unroll
    for (int i = 0; i < 16; ++i) {
        float4 v = base[i * 256 + tid];
        s += v.x + v.y + v.z + v.w;
        sq += v.x * v.x + v.y * v.y + v.z * v.z + v.w * v.w;
    }
    __shared__ float ls[4], lq[4];
    s = wave_sum(s);
    sq = wave_sum(sq);
    int wid = tid >> 6, lane = tid & 63;
    if (lane == 0) { ls[wid] = s; lq[wid] = sq; }
    __syncthreads();
    if (tid == 0) {
        partials[blk * 2 + 0] = ls[0] + ls[1] + ls[2] + ls[3];
        partials[blk * 2 + 1] = lq[0] + lq[1] + lq[2] + lq[3];
    }
}

// ---------- Kernel A2: finalize mu / rsqrt ----------
__global__ void feat_stats_final(const float* __restrict__ partials,
                                 float* __restrict__ mu_rs) {
    int g = threadIdx.x; // 64
    float s = 0.f, sq = 0.f;
#pragma unroll
    for (int c = 0; c < 16; ++c) {
        s  += partials[(g * 16 + c) * 2 + 0];
        sq += partials[(g * 16 + c) * 2 + 1];
    }
    const float inv = 1.f / 262144.f;
    float mu = s * inv;
    float var = sq * inv - mu * mu;
    mu_rs[g * 2 + 0] = mu;
    mu_rs[g * 2 + 1] = rsqrtf(var + 1e-5f);
}

// ---------- Kernel B1: dec4 GN + ReLU + spatial mean -> g (4,512) ----------
// dec4: (4,512,16,16) = (4,512,256). One block per (b,group): 32ch*256px
// contiguous 8192 floats.
__global__ __launch_bounds__(256) void dec4_gap(
    const float* __restrict__ dec4, const float* __restrict__ gamma,
    const float* __restrict__ beta, float* __restrict__ g_out) {
    int blk = blockIdx.x;           // b*16+gi
    int b = blk >> 4, gi = blk & 15;
    const float* base = dec4 + (size_t)blk * 8192;
    int tid = threadIdx.x;
    int wid = tid >> 6, lane = tid & 63;

    float vals[32];
    float s = 0.f, sq = 0.f;
#pragma unroll
    for (int ch = 0; ch < 32; ++ch) {
        float v = base[ch * 256 + tid];
        vals[ch] = v;
        s += v; sq += v * v;
    }
    __shared__ float ls[4], lq[4], bc[2], red[4];
    s = wave_sum(s); sq = wave_sum(sq);
    if (lane == 0) { ls[wid] = s; lq[wid] = sq; }
    __syncthreads();
    if (tid == 0) {
        float S = ls[0] + ls[1] + ls[2] + ls[3];
        float Q = lq[0] + lq[1] + lq[2] + lq[3];
        const float inv = 1.f / 8192.f;
        float mu = S * inv;
        float var = Q * inv - mu * mu;
        bc[0] = mu;
        bc[1] = rsqrtf(var + 1e-5f);
    }
    __syncthreads();
    float mu = bc[0], rs = bc[1];

    for (int ch = 0; ch < 32; ++ch) {
        int c = gi * 32 + ch;
        float sc = rs * gamma[c];
        float sh = beta[c] - mu * sc;
        float r = fmaxf(vals[ch] * sc + sh, 0.f);
        r = wave_sum(r);
        if (lane == 0) red[wid] = r;
        __syncthreads();
        if (tid == 0)
            g_out[b * 512 + c] = (red[0] + red[1] + red[2] + red[3]) * (1.f / 256.f);
        __syncthreads();
    }
}

// ---------- Kernel B2: x_feat = g @ W_gap.T + b_gap  (4,256) ----------
__global__ __launch_bounds__(256) void gap_fc(
    const float* __restrict__ g_in, const float* __restrict__ W_gap,
    const float* __restrict__ b_gap, float* __restrict__ x_feat) {
    int b = blockIdx.x, o = threadIdx.x;
    __shared__ float gs[512];
    gs[o] = g_in[b * 512 + o];
    gs[o + 256] = g_in[b * 512 + o + 256];
    __syncthreads();
    float acc = b_gap[o];
    for (int k = 0; k < 512; ++k) acc += gs[k] * W_gap[o * 512 + k];
    x_feat[b * 256 + o] = acc;
}

// ---------- Kernel B3: params (4,32,153) ----------
__global__ __launch_bounds__(256) void ctrl_fc(
    const float* __restrict__ x_feat, const float* __restrict__ emb,
    const float* __restrict__ W_ctrl, const float* __restrict__ b_ctrl,
    float* __restrict__ params) {
    int bc_i = blockIdx.x;          // b*32+c
    int b = bc_i >> 5, c = bc_i & 31;
    int tid = threadIdx.x;
    __shared__ float xc[512];
    xc[tid] = x_feat[b * 256 + tid];
    xc[256 + tid] = emb[c * 256 + tid];
    __syncthreads();
    if (tid < 153) {
        float acc = b_ctrl[tid];
        const float* w = W_ctrl + tid * 512;
        for (int k = 0; k < 512; ++k) acc += w[k] * xc[k];
        params[(size_t)bc_i * 153 + tid] = acc;
    }
}

// ---------- Kernel C: main fused pixel kernel ----------
// grid = 4 * 256 blocks, 256 thr, one pixel per thread.
__global__ __launch_bounds__(256) void main_fused(
    const float* __restrict__ feat, const float* __restrict__ mu_rs,
    const float* __restrict__ gamma, const float* __restrict__ beta,
    const float* __restrict__ W_pre, const float* __restrict__ b_pre,
    const float* __restrict__ params, float* __restrict__ out) {
    int blk = blockIdx.x;           // 0..1023
    int b = blk >> 8;
    int p = ((blk & 255) << 8) + threadIdx.x;

    __shared__ float sc[64], sh[64];
    if (threadIdx.x < 64) {
        int ch = threadIdx.x;
        int g = b * 16 + (ch >> 2);
        float mu = mu_rs[g * 2 + 0];
        float rs = mu_rs[g * 2 + 1];
        float s = rs * gamma[ch];
        sc[ch] = s;
        sh[ch] = beta[ch] - mu * s;
    }
    __syncthreads();

    float hi[8];
#pragma unroll
    for (int o = 0; o < 8; ++o) hi[o] = b_pre[o];

    const float* fb = feat + ((size_t)b << 22) + p;
#pragma unroll
    for (int ch = 0; ch < 64; ++ch) {
        float v = fb[(size_t)ch << 16];
        float pre = fmaxf(v * sc[ch] + sh[ch], 0.f);
#pragma unroll
        for (int o = 0; o < 8; ++o) hi[o] += W_pre[o * 64 + ch] * pre;
    }

    float* ob = out + ((size_t)b << 21) + p;
    for (int c = 0; c < 32; ++c) {
        const float* P = params + (size_t)(b * 32 + c) * 153;
        float x1[8], x2[8];
#pragma unroll
        for (int o = 0; o < 8; ++o) {
            float a = P[136 + o];
#pragma unroll
            for (int i = 0; i < 8; ++i) a += P[o * 8 + i] * hi[i];
            x1[o] = fmaxf(a, 0.f);
        }
#pragma unroll
        for (int o = 0; o < 8; ++o) {
            float a = P[144 + o];
#pragma unroll
            for (int i = 0; i < 8; ++i) a += P[64 + o * 8 + i] * x1[i];
            x2[o] = fmaxf(a, 0.f);
        }
        float lg = P[152];
#pragma unroll
        for (int i = 0; i < 8; ++i) lg += P[128 + i] * x2[i];
        ob[(size_t)c << 16] = lg;
    }
}

// ---------- launch ----------
extern "C" void kernel_launch(void* const* d_in, const int* in_sizes, int n_in,
                              void* d_out, int out_size, void* d_ws, size_t ws_size,
                              hipStream_t stream) {
    const float* dec4         = (const float*)d_in[0];
    const float* feat         = (const float*)d_in[1];
    const float* gn_pre_gamma = (const float*)d_in[2];
    const float* gn_pre_beta  = (const float*)d_in[3];
    const float* W_pre        = (const float*)d_in[4];
    const float* b_pre        = (const float*)d_in[5];
    const float* gn_gap_gamma = (const float*)d_in[6];
    const float* gn_gap_beta  = (const float*)d_in[7];
    const float* W_gap        = (const float*)d_in[8];
    const float* b_gap        = (const float*)d_in[9];
    const float* emb          = (const float*)d_in[10];
    const float* W_ctrl       = (const float*)d_in[11];
    const float* b_ctrl       = (const float*)d_in[12];
    float* out = (float*)d_out;
    float* ws  = (float*)d_ws;

    float* partials = ws;          // 2048
    float* mu_rs    = ws + 2048;   // 128
    float* g_buf    = ws + 2176;   // 2048
    float* x_feat   = ws + 4224;   // 1024
    float* params   = ws + 5248;   // 19584

    feat_stats_partial<<<1024, 256, 0, stream>>>(feat, partials);
    feat_stats_final<<<1, 64, 0, stream>>>(partials, mu_rs);
    dec4_gap<<<64, 256, 0, stream>>>(dec4, gn_gap_gamma, gn_gap_beta, g_buf);
    gap_fc<<<4, 256, 0, stream>>>(g_buf, W_gap, b_gap, x_feat);
    ctrl_fc<<<128, 256, 0, stream>>>(x_feat, emb, W_ctrl, b_ctrl, params);
    main_fused<<<1024, 256, 0, stream>>>(feat, mu_rs, gn_pre_gamma, gn_pre_beta,
                                         W_pre, b_pre, params, out);
}

// Round 3
// 117.650 us; speedup vs baseline: 1.5027x; 1.5027x over previous
//
#include <hip/hip_runtime.h>
#include <hip/hip_bf16.h>

__device__ inline float wave_sum(float v) {
#pragma unroll
    for (int off = 32; off > 0; off >>= 1) v += __shfl_down(v, off, 64);
    return v;
}

// ---------------- Kernel 1: prep ----------------
// blk <1024  : feat group-stat partials (feat (4,64,256,256), 64 groups x 16 chunks)
// 1024..1087 : dec4 GN+ReLU+GAP -> g_buf (4,512)
// 1088..1119 : E[c,o] = sum_k W_ctrl[o,256+k]*emb[c,k]   (32 blocks)
__global__ __launch_bounds__(256) void prep(
    const float* __restrict__ feat, const float* __restrict__ dec4,
    const float* __restrict__ gn_gap_gamma, const float* __restrict__ gn_gap_beta,
    const float* __restrict__ emb, const float* __restrict__ W_ctrl,
    float* __restrict__ partials, float* __restrict__ g_buf,
    float* __restrict__ E_buf) {
    int blk = blockIdx.x;
    int tid = threadIdx.x;
    if (blk < 1024) {
        int grp = blk >> 4;     // b*16+g
        int chunk = blk & 15;
        const float4* base = (const float4*)(feat + (size_t)grp * 262144 + (size_t)chunk * 16384);
        float s = 0.f, sq = 0.f;
#pragma unroll
        for (int i = 0; i < 16; ++i) {
            float4 v = base[i * 256 + tid];
            s += v.x + v.y + v.z + v.w;
            sq += v.x * v.x + v.y * v.y + v.z * v.z + v.w * v.w;
        }
        __shared__ float ls[4], lq[4];
        s = wave_sum(s); sq = wave_sum(sq);
        int wid = tid >> 6, lane = tid & 63;
        if (lane == 0) { ls[wid] = s; lq[wid] = sq; }
        __syncthreads();
        if (tid == 0) {
            partials[blk * 2 + 0] = ls[0] + ls[1] + ls[2] + ls[3];
            partials[blk * 2 + 1] = lq[0] + lq[1] + lq[2] + lq[3];
        }
    } else if (blk < 1088) {
        int blk2 = blk - 1024;          // b*16+gi
        int b = blk2 >> 4, gi = blk2 & 15;
        const float* base = dec4 + (size_t)blk2 * 8192;
        int wid = tid >> 6, lane = tid & 63;
        float vals[32];
        float s = 0.f, sq = 0.f;
#pragma unroll
        for (int ch = 0; ch < 32; ++ch) {
            float v = base[ch * 256 + tid];
            vals[ch] = v;
            s += v; sq += v * v;
        }
        __shared__ float ls2[4], lq2[4], bc[2], red[4];
        s = wave_sum(s); sq = wave_sum(sq);
        if (lane == 0) { ls2[wid] = s; lq2[wid] = sq; }
        __syncthreads();
        if (tid == 0) {
            float S = ls2[0] + ls2[1] + ls2[2] + ls2[3];
            float Q = lq2[0] + lq2[1] + lq2[2] + lq2[3];
            const float inv = 1.f / 8192.f;
            float mu = S * inv;
            float var = Q * inv - mu * mu;
            bc[0] = mu;
            bc[1] = rsqrtf(var + 1e-5f);
        }
        __syncthreads();
        float mu = bc[0], rs = bc[1];
        for (int ch = 0; ch < 32; ++ch) {
            int c = gi * 32 + ch;
            float scv = rs * gn_gap_gamma[c];
            float shv = gn_gap_beta[c] - mu * scv;
            float r = fmaxf(vals[ch] * scv + shv, 0.f);
            r = wave_sum(r);
            if (lane == 0) red[wid] = r;
            __syncthreads();
            if (tid == 0)
                g_buf[b * 512 + c] = (red[0] + red[1] + red[2] + red[3]) * (1.f / 256.f);
            __syncthreads();
        }
    } else {
        int c = blk - 1088;
        __shared__ float es[256];
        es[tid] = emb[c * 256 + tid];
        __syncthreads();
        if (tid < 153) {
            const float4* w = (const float4*)(W_ctrl + tid * 512 + 256);
            const float4* e4 = (const float4*)es;
            float acc = 0.f;
#pragma unroll 8
            for (int k = 0; k < 64; ++k) {
                float4 wv = w[k], ev = e4[k];
                acc += wv.x * ev.x + wv.y * ev.y + wv.z * ev.z + wv.w * ev.w;
            }
            E_buf[c * 153 + tid] = acc;
        }
    }
}

// ---------------- Kernel 2: fc ----------------
// 4 blocks (one per b): x_feat = g@W_gap.T + b_gap; F[o] = W_ctrl[o,:256]·x_feat
// + b_ctrl[o]; params_padded[b,c,o<160] = F[o] + E[c,o] (pad 153..159 = 0)
__global__ __launch_bounds__(256) void fc(
    const float* __restrict__ g_buf, const float* __restrict__ W_gap,
    const float* __restrict__ b_gap, const float* __restrict__ W_ctrl,
    const float* __restrict__ b_ctrl, const float* __restrict__ E_buf,
    float* __restrict__ params) {
    int b = blockIdx.x, tid = threadIdx.x;
    __shared__ float gs[512];
    __shared__ float xf[256];
    __shared__ float F[160];
    gs[tid] = g_buf[b * 512 + tid];
    gs[tid + 256] = g_buf[b * 512 + 256 + tid];
    __syncthreads();
    {
        const float4* w = (const float4*)(W_gap + tid * 512);
        const float4* g4 = (const float4*)gs;
        float acc = b_gap[tid];
#pragma unroll 8
        for (int k = 0; k < 128; ++k) {
            float4 wv = w[k], gv = g4[k];
            acc += wv.x * gv.x + wv.y * gv.y + wv.z * gv.z + wv.w * gv.w;
        }
        xf[tid] = acc;
    }
    __syncthreads();
    if (tid < 160) {
        float acc = 0.f;
        if (tid < 153) {
            const float4* w = (const float4*)(W_ctrl + tid * 512);
            const float4* x4 = (const float4*)xf;
#pragma unroll 8
            for (int k = 0; k < 64; ++k) {
                float4 wv = w[k], xv = x4[k];
                acc += wv.x * xv.x + wv.y * xv.y + wv.z * xv.z + wv.w * xv.w;
            }
            acc += b_ctrl[tid];
        }
        F[tid] = acc;
    }
    __syncthreads();
    for (int i = tid; i < 5120; i += 256) {
        int c = i / 160, o = i - c * 160;
        float v = F[o];
        if (o < 153) v += E_buf[c * 153 + o];
        params[(size_t)b * 5120 + i] = v;
    }
}

// ---------------- Kernel 3: main fused ----------------
// 512 blocks x 256 thr, 2 adjacent pixels per thread (float2 I/O).
// Params for batch b staged in LDS (32 x 160 floats, float4-aligned layout:
// [0:64) w1 | [64:128) w2 | [128:136) w3 | [136:144) b1 | [144:152) b2 | [152] b3)
__global__ __launch_bounds__(256) void main_fused(
    const float* __restrict__ feat, const float* __restrict__ partials,
    const float* __restrict__ gamma, const float* __restrict__ beta,
    const float* __restrict__ W_pre, const float* __restrict__ b_pre,
    const float* __restrict__ params, float* __restrict__ out) {
    int blk = blockIdx.x;            // 0..511
    int b = blk >> 7;
    int tid = threadIdx.x;
    int p0 = ((blk & 127) << 9) + tid * 2;

    __shared__ float4 pp[1280];      // 20 KB
    __shared__ float sc[64], sh[64];
    __shared__ float mu_s[16], rs_s[16];

    const float4* src = (const float4*)(params + (size_t)b * 5120);
#pragma unroll
    for (int i = 0; i < 5; ++i) pp[tid + 256 * i] = src[tid + 256 * i];

    if (tid < 16) {
        float s = 0.f, q = 0.f;
#pragma unroll
        for (int c = 0; c < 16; ++c) {
            int idx = ((b * 16 + tid) * 16 + c) * 2;
            s += partials[idx];
            q += partials[idx + 1];
        }
        const float inv = 1.f / 262144.f;
        float mu = s * inv;
        float var = q * inv - mu * mu;
        mu_s[tid] = mu;
        rs_s[tid] = rsqrtf(var + 1e-5f);
    }
    __syncthreads();
    if (tid < 64) {
        float mu = mu_s[tid >> 2], rs = rs_s[tid >> 2];
        float s = rs * gamma[tid];
        sc[tid] = s;
        sh[tid] = beta[tid] - mu * s;
    }
    __syncthreads();

    float hi0[8], hi1[8];
#pragma unroll
    for (int o = 0; o < 8; ++o) { float bv = b_pre[o]; hi0[o] = bv; hi1[o] = bv; }

    const float* fb = feat + ((size_t)b << 22) + p0;
#pragma unroll
    for (int ch = 0; ch < 64; ++ch) {
        float2 v = *(const float2*)(fb + ((size_t)ch << 16));
        float s = sc[ch], h = sh[ch];
        float pre0 = fmaxf(v.x * s + h, 0.f);
        float pre1 = fmaxf(v.y * s + h, 0.f);
#pragma unroll
        for (int o = 0; o < 8; ++o) {
            float w = W_pre[o * 64 + ch];
            hi0[o] += w * pre0;
            hi1[o] += w * pre1;
        }
    }

    float* ob = out + ((size_t)b << 21) + p0;
    for (int c = 0; c < 32; ++c) {
        const float4* Pc = pp + c * 40;
        float4 t;
        float b1v[8], b2v[8];
        t = Pc[34]; b1v[0] = t.x; b1v[1] = t.y; b1v[2] = t.z; b1v[3] = t.w;
        t = Pc[35]; b1v[4] = t.x; b1v[5] = t.y; b1v[6] = t.z; b1v[7] = t.w;
        t = Pc[36]; b2v[0] = t.x; b2v[1] = t.y; b2v[2] = t.z; b2v[3] = t.w;
        t = Pc[37]; b2v[4] = t.x; b2v[5] = t.y; b2v[6] = t.z; b2v[7] = t.w;
        float b3v = Pc[38].x;

        float x1_0[8], x1_1[8];
#pragma unroll
        for (int o = 0; o < 8; ++o) {
            float4 wa = Pc[o * 2], wb = Pc[o * 2 + 1];
            float a0 = b1v[o]
                + wa.x * hi0[0] + wa.y * hi0[1] + wa.z * hi0[2] + wa.w * hi0[3]
                + wb.x * hi0[4] + wb.y * hi0[5] + wb.z * hi0[6] + wb.w * hi0[7];
            float a1 = b1v[o]
                + wa.x * hi1[0] + wa.y * hi1[1] + wa.z * hi1[2] + wa.w * hi1[3]
                + wb.x * hi1[4] + wb.y * hi1[5] + wb.z * hi1[6] + wb.w * hi1[7];
            x1_0[o] = fmaxf(a0, 0.f);
            x1_1[o] = fmaxf(a1, 0.f);
        }
        float x2_0[8], x2_1[8];
#pragma unroll
        for (int o = 0; o < 8; ++o) {
            float4 wa = Pc[16 + o * 2], wb = Pc[17 + o * 2];
            float a0 = b2v[o]
                + wa.x * x1_0[0] + wa.y * x1_0[1] + wa.z * x1_0[2] + wa.w * x1_0[3]
                + wb.x * x1_0[4] + wb.y * x1_0[5] + wb.z * x1_0[6] + wb.w * x1_0[7];
            float a1 = b2v[o]
                + wa.x * x1_1[0] + wa.y * x1_1[1] + wa.z * x1_1[2] + wa.w * x1_1[3]
                + wb.x * x1_1[4] + wb.y * x1_1[5] + wb.z * x1_1[6] + wb.w * x1_1[7];
            x2_0[o] = fmaxf(a0, 0.f);
            x2_1[o] = fmaxf(a1, 0.f);
        }
        float4 w3a = Pc[32], w3b = Pc[33];
        float lg0 = b3v
            + w3a.x * x2_0[0] + w3a.y * x2_0[1] + w3a.z * x2_0[2] + w3a.w * x2_0[3]
            + w3b.x * x2_0[4] + w3b.y * x2_0[5] + w3b.z * x2_0[6] + w3b.w * x2_0[7];
        float lg1 = b3v
            + w3a.x * x2_1[0] + w3a.y * x2_1[1] + w3a.z * x2_1[2] + w3a.w * x2_1[3]
            + w3b.x * x2_1[4] + w3b.y * x2_1[5] + w3b.z * x2_1[6] + w3b.w * x2_1[7];
        *(float2*)(ob + ((size_t)c << 16)) = make_float2(lg0, lg1);
    }
}

// ---------------- launch ----------------
extern "C" void kernel_launch(void* const* d_in, const int* in_sizes, int n_in,
                              void* d_out, int out_size, void* d_ws, size_t ws_size,
                              hipStream_t stream) {
    const float* dec4         = (const float*)d_in[0];
    const float* feat         = (const float*)d_in[1];
    const float* gn_pre_gamma = (const float*)d_in[2];
    const float* gn_pre_beta  = (const float*)d_in[3];
    const float* W_pre        = (const float*)d_in[4];
    const float* b_pre        = (const float*)d_in[5];
    const float* gn_gap_gamma = (const float*)d_in[6];
    const float* gn_gap_beta  = (const float*)d_in[7];
    const float* W_gap        = (const float*)d_in[8];
    const float* b_gap        = (const float*)d_in[9];
    const float* emb          = (const float*)d_in[10];
    const float* W_ctrl       = (const float*)d_in[11];
    const float* b_ctrl       = (const float*)d_in[12];
    float* out = (float*)d_out;
    float* ws  = (float*)d_ws;

    float* partials = ws;           // 2048 floats
    float* g_buf    = ws + 2048;    // 2048
    float* E_buf    = ws + 4096;    // 4896
    float* params   = ws + 9216;    // 20480 (16B-aligned, padded stride 160)

    prep<<<1120, 256, 0, stream>>>(feat, dec4, gn_gap_gamma, gn_gap_beta,
                                   emb, W_ctrl, partials, g_buf, E_buf);
    fc<<<4, 256, 0, stream>>>(g_buf, W_gap, b_gap, W_ctrl, b_ctrl, E_buf, params);
    main_fused<<<512, 256, 0, stream>>>(feat, partials, gn_pre_gamma, gn_pre_beta,
                                        W_pre, b_pre, params, out);
}

// Round 5
// 99.147 us; speedup vs baseline: 1.7831x; 1.1866x over previous
//
#include <hip/hip_runtime.h>
#include <hip/hip_bf16.h>
#include <hip/hip_fp16.h>

typedef __fp16 h2 __attribute__((ext_vector_type(2)));

#if defined(__has_builtin)
#if __has_builtin(__builtin_amdgcn_fdot2)
#define HAVE_FDOT2 1
#endif
#endif

__device__ inline float dot2f(h2 a, h2 b, float acc) {
#ifdef HAVE_FDOT2
    return __builtin_amdgcn_fdot2(a, b, acc, false);
#else
    return acc + (float)a.x * (float)b.x + (float)a.y * (float)b.y;
#endif
}

__device__ inline float wave_sum(float v) {
#pragma unroll
    for (int off = 32; off > 0; off >>= 1) v += __shfl_down(v, off, 64);
    return v;
}

// ---------------- Kernel 1: prep ----------------
__global__ __launch_bounds__(256) void prep(
    const float* __restrict__ feat, const float* __restrict__ dec4,
    const float* __restrict__ gn_gap_gamma, const float* __restrict__ gn_gap_beta,
    const float* __restrict__ emb, const float* __restrict__ W_ctrl,
    float* __restrict__ partials, float* __restrict__ g_buf,
    float* __restrict__ E_buf) {
    int blk = blockIdx.x;
    int tid = threadIdx.x;
    if (blk < 1024) {
        int grp = blk >> 4;
        int chunk = blk & 15;
        const float4* base = (const float4*)(feat + (size_t)grp * 262144 + (size_t)chunk * 16384);
        float s = 0.f, sq = 0.f;
#pragma unroll
        for (int i = 0; i < 16; ++i) {
            float4 v = base[i * 256 + tid];
            s += v.x + v.y + v.z + v.w;
            sq += v.x * v.x + v.y * v.y + v.z * v.z + v.w * v.w;
        }
        __shared__ float ls[4], lq[4];
        s = wave_sum(s); sq = wave_sum(sq);
        int wid = tid >> 6, lane = tid & 63;
        if (lane == 0) { ls[wid] = s; lq[wid] = sq; }
        __syncthreads();
        if (tid == 0) {
            partials[blk * 2 + 0] = ls[0] + ls[1] + ls[2] + ls[3];
            partials[blk * 2 + 1] = lq[0] + lq[1] + lq[2] + lq[3];
        }
    } else if (blk < 1088) {
        int blk2 = blk - 1024;
        int b = blk2 >> 4, gi = blk2 & 15;
        const float* base = dec4 + (size_t)blk2 * 8192;
        int wid = tid >> 6, lane = tid & 63;
        float vals[32];
        float s = 0.f, sq = 0.f;
#pragma unroll
        for (int ch = 0; ch < 32; ++ch) {
            float v = base[ch * 256 + tid];
            vals[ch] = v;
            s += v; sq += v * v;
        }
        __shared__ float ls2[4], lq2[4], bc[2], red[4];
        s = wave_sum(s); sq = wave_sum(sq);
        if (lane == 0) { ls2[wid] = s; lq2[wid] = sq; }
        __syncthreads();
        if (tid == 0) {
            float S = ls2[0] + ls2[1] + ls2[2] + ls2[3];
            float Q = lq2[0] + lq2[1] + lq2[2] + lq2[3];
            const float inv = 1.f / 8192.f;
            float mu = S * inv;
            float var = Q * inv - mu * mu;
            bc[0] = mu;
            bc[1] = rsqrtf(var + 1e-5f);
        }
        __syncthreads();
        float mu = bc[0], rs = bc[1];
        for (int ch = 0; ch < 32; ++ch) {
            int c = gi * 32 + ch;
            float scv = rs * gn_gap_gamma[c];
            float shv = gn_gap_beta[c] - mu * scv;
            float r = fmaxf(vals[ch] * scv + shv, 0.f);
            r = wave_sum(r);
            if (lane == 0) red[wid] = r;
            __syncthreads();
            if (tid == 0)
                g_buf[b * 512 + c] = (red[0] + red[1] + red[2] + red[3]) * (1.f / 256.f);
            __syncthreads();
        }
    } else {
        int c = blk - 1088;
        __shared__ float es[256];
        es[tid] = emb[c * 256 + tid];
        __syncthreads();
        if (tid < 153) {
            const float4* w = (const float4*)(W_ctrl + tid * 512 + 256);
            const float4* e4 = (const float4*)es;
            float acc = 0.f;
#pragma unroll 8
            for (int k = 0; k < 64; ++k) {
                float4 wv = w[k], ev = e4[k];
                acc += wv.x * ev.x + wv.y * ev.y + wv.z * ev.z + wv.w * ev.w;
            }
            E_buf[c * 153 + tid] = acc;
        }
    }
}

// ---------------- Kernel 2: fc -> packed f16 params ----------------
// Per (b,c), 320 bytes: f16[152] at byte 2*i (W1 rows|W2 rows|W3|b1|b2),
// f32 b3 at byte 304, pad to 320.
__global__ __launch_bounds__(256) void fc(
    const float* __restrict__ g_buf, const float* __restrict__ W_gap,
    const float* __restrict__ b_gap, const float* __restrict__ W_ctrl,
    const float* __restrict__ b_ctrl, const float* __restrict__ E_buf,
    unsigned char* __restrict__ pk) {
    int b = blockIdx.x, tid = threadIdx.x;
    __shared__ float gs[512];
    __shared__ float xf[256];
    __shared__ float F[160];
    gs[tid] = g_buf[b * 512 + tid];
    gs[tid + 256] = g_buf[b * 512 + 256 + tid];
    __syncthreads();
    {
        const float4* w = (const float4*)(W_gap + tid * 512);
        const float4* g4 = (const float4*)gs;
        float acc = b_gap[tid];
#pragma unroll 8
        for (int k = 0; k < 128; ++k) {
            float4 wv = w[k], gv = g4[k];
            acc += wv.x * gv.x + wv.y * gv.y + wv.z * gv.z + wv.w * gv.w;
        }
        xf[tid] = acc;
    }
    __syncthreads();
    if (tid < 160) {
        float acc = 0.f;
        if (tid < 153) {
            const float4* w = (const float4*)(W_ctrl + tid * 512);
            const float4* x4 = (const float4*)xf;
#pragma unroll 8
            for (int k = 0; k < 64; ++k) {
                float4 wv = w[k], xv = x4[k];
                acc += wv.x * xv.x + wv.y * xv.y + wv.z * xv.z + wv.w * xv.w;
            }
            acc += b_ctrl[tid];
        }
        F[tid] = acc;
    }
    __syncthreads();
    unsigned char* dst = pk + (size_t)b * 10240;
    for (int c = 0; c < 32; ++c) {
        if (tid < 152) {
            float v = F[tid] + E_buf[c * 153 + tid];
            ((__fp16*)(dst + c * 320))[tid] = (__fp16)v;
        } else if (tid == 152) {
            *(float*)(dst + c * 320 + 304) = F[152] + E_buf[c * 153 + 152];
        }
    }
}

// ---------------- Kernel 3: main fused ----------------
// 512 blocks x 256 thr. Block: 512-px tile of batch b.
// Phase 1 (all 4 waves): head -> hi (8 f16 per px) into LDS.
// Phase 2: wave w handles c in [8w, 8w+8) for all 512 px; weights read once
// per c per wave from LDS (f16-packed), math via v_dot2_f32_f16.
__global__ __launch_bounds__(256) void main_fused(
    const float* __restrict__ feat, const float* __restrict__ partials,
    const float* __restrict__ gamma, const float* __restrict__ beta,
    const float* __restrict__ W_pre, const float* __restrict__ b_pre,
    const float4* __restrict__ pk, float* __restrict__ out) {
    int blk = blockIdx.x;            // 0..511
    int b = blk >> 7;
    int tid = threadIdx.x;
    int wv = tid >> 6, lane = tid & 63;
    int P0 = (blk & 127) << 9;       // 512-px tile base

    __shared__ float4 pp[640];       // 10240 B packed params for batch b
    __shared__ float4 hi_lds[512];   // 8192 B: [pairidx] even-px hi, [256+pairidx] odd-px
    __shared__ float sc[64], sh[64];
    __shared__ float mu_s[16], rs_s[16];

    // stage packed params
    const float4* src = pk + (size_t)b * 640;
    for (int i = tid; i < 640; i += 256) pp[i] = src[i];

    // group stats
    if (tid < 16) {
        float s = 0.f, q = 0.f;
#pragma unroll
        for (int c = 0; c < 16; ++c) {
            int idx = ((b * 16 + tid) * 16 + c) * 2;
            s += partials[idx];
            q += partials[idx + 1];
        }
        const float inv = 1.f / 262144.f;
        float mu = s * inv;
        float var = q * inv - mu * mu;
        mu_s[tid] = mu;
        rs_s[tid] = rsqrtf(var + 1e-5f);
    }
    __syncthreads();
    if (tid < 64) {
        float mu = mu_s[tid >> 2], rs = rs_s[tid >> 2];
        float s = rs * gamma[tid];
        sc[tid] = s;
        sh[tid] = beta[tid] - mu * s;
    }
    __syncthreads();

    // ---- phase 1: head for this thread's 2 px ----
    {
        int p0 = P0 + tid * 2;
        float hi0[8], hi1[8];
#pragma unroll
        for (int o = 0; o < 8; ++o) { float bv = b_pre[o]; hi0[o] = bv; hi1[o] = bv; }
        const float* fb = feat + ((size_t)b << 22) + p0;
#pragma unroll
        for (int ch = 0; ch < 64; ++ch) {
            float2 v = *(const float2*)(fb + ((size_t)ch << 16));
            float s = sc[ch], h = sh[ch];
            float pre0 = fmaxf(v.x * s + h, 0.f);
            float pre1 = fmaxf(v.y * s + h, 0.f);
#pragma unroll
            for (int o = 0; o < 8; ++o) {
                float w = W_pre[o * 64 + ch];
                hi0[o] += w * pre0;
                hi1[o] += w * pre1;
            }
        }
        float4 h0, h1;
        h0.x = __builtin_bit_cast(float, __builtin_amdgcn_cvt_pkrtz(hi0[0], hi0[1]));
        h0.y = __builtin_bit_cast(float, __builtin_amdgcn_cvt_pkrtz(hi0[2], hi0[3]));
        h0.z = __builtin_bit_cast(float, __builtin_amdgcn_cvt_pkrtz(hi0[4], hi0[5]));
        h0.w = __builtin_bit_cast(float, __builtin_amdgcn_cvt_pkrtz(hi0[6], hi0[7]));
        h1.x = __builtin_bit_cast(float, __builtin_amdgcn_cvt_pkrtz(hi1[0], hi1[1]));
        h1.y = __builtin_bit_cast(float, __builtin_amdgcn_cvt_pkrtz(hi1[2], hi1[3]));
        h1.z = __builtin_bit_cast(float, __builtin_amdgcn_cvt_pkrtz(hi1[4], hi1[5]));
        h1.w = __builtin_bit_cast(float, __builtin_amdgcn_cvt_pkrtz(hi1[6], hi1[7]));
        hi_lds[tid] = h0;        // even px (P0 + 2*tid)
        hi_lds[256 + tid] = h1;  // odd px
    }
    __syncthreads();

    // ---- phase 2: this wave's 8 c over all 512 px ----
    float* ob = out + ((size_t)b << 21) + P0;
#pragma unroll 1
    for (int k = 0; k < 8; ++k) {
        int c = wv * 8 + k;
        const float4* Pc = pp + c * 20;
        float4 w1r[8], w2r[8];
#pragma unroll
        for (int o = 0; o < 8; ++o) w1r[o] = Pc[o];
#pragma unroll
        for (int o = 0; o < 8; ++o) w2r[o] = Pc[8 + o];
        float4 w3r = Pc[16];
        float4 b1r = Pc[17];
        float4 b2r = Pc[18];
        float b3v = Pc[19].x;
        float b1f[8], b2f[8];
        { h2 t = __builtin_bit_cast(h2, b1r.x); b1f[0] = t.x; b1f[1] = t.y; }
        { h2 t = __builtin_bit_cast(h2, b1r.y); b1f[2] = t.x; b1f[3] = t.y; }
        { h2 t = __builtin_bit_cast(h2, b1r.z); b1f[4] = t.x; b1f[5] = t.y; }
        { h2 t = __builtin_bit_cast(h2, b1r.w); b1f[6] = t.x; b1f[7] = t.y; }
        { h2 t = __builtin_bit_cast(h2, b2r.x); b2f[0] = t.x; b2f[1] = t.y; }
        { h2 t = __builtin_bit_cast(h2, b2r.y); b2f[2] = t.x; b2f[3] = t.y; }
        { h2 t = __builtin_bit_cast(h2, b2r.z); b2f[4] = t.x; b2f[5] = t.y; }
        { h2 t = __builtin_bit_cast(h2, b2r.w); b2f[6] = t.x; b2f[7] = t.y; }

        float* cp = ob + ((size_t)c << 16);
#pragma unroll
        for (int j = 0; j < 4; ++j) {
            int q = j * 64 + lane;   // pair index 0..255
            float4 ha = hi_lds[q];
            float4 hb = hi_lds[256 + q];
            h2 a0 = __builtin_bit_cast(h2, ha.x), a1 = __builtin_bit_cast(h2, ha.y),
               a2 = __builtin_bit_cast(h2, ha.z), a3 = __builtin_bit_cast(h2, ha.w);
            h2 e0 = __builtin_bit_cast(h2, hb.x), e1 = __builtin_bit_cast(h2, hb.y),
               e2 = __builtin_bit_cast(h2, hb.z), e3 = __builtin_bit_cast(h2, hb.w);

            float x1a[8], x1b[8];
#pragma unroll
            for (int o = 0; o < 8; ++o) {
                h2 wa = __builtin_bit_cast(h2, w1r[o].x), wb = __builtin_bit_cast(h2, w1r[o].y),
                   wc = __builtin_bit_cast(h2, w1r[o].z), wd = __builtin_bit_cast(h2, w1r[o].w);
                float s0 = dot2f(wd, a3, dot2f(wc, a2, dot2f(wb, a1, dot2f(wa, a0, b1f[o]))));
                float s1 = dot2f(wd, e3, dot2f(wc, e2, dot2f(wb, e1, dot2f(wa, e0, b1f[o]))));
                x1a[o] = fmaxf(s0, 0.f);
                x1b[o] = fmaxf(s1, 0.f);
            }
            h2 pa0 = __builtin_amdgcn_cvt_pkrtz(x1a[0], x1a[1]);
            h2 pa1 = __builtin_amdgcn_cvt_pkrtz(x1a[2], x1a[3]);
            h2 pa2 = __builtin_amdgcn_cvt_pkrtz(x1a[4], x1a[5]);
            h2 pa3 = __builtin_amdgcn_cvt_pkrtz(x1a[6], x1a[7]);
            h2 pb0 = __builtin_amdgcn_cvt_pkrtz(x1b[0], x1b[1]);
            h2 pb1 = __builtin_amdgcn_cvt_pkrtz(x1b[2], x1b[3]);
            h2 pb2 = __builtin_amdgcn_cvt_pkrtz(x1b[4], x1b[5]);
            h2 pb3 = __builtin_amdgcn_cvt_pkrtz(x1b[6], x1b[7]);

            float x2a[8], x2b[8];
#pragma unroll
            for (int o = 0; o < 8; ++o) {
                h2 wa = __builtin_bit_cast(h2, w2r[o].x), wb = __builtin_bit_cast(h2, w2r[o].y),
                   wc = __builtin_bit_cast(h2, w2r[o].z), wd = __builtin_bit_cast(h2, w2r[o].w);
                float s0 = dot2f(wd, pa3, dot2f(wc, pa2, dot2f(wb, pa1, dot2f(wa, pa0, b2f[o]))));
                float s1 = dot2f(wd, pb3, dot2f(wc, pb2, dot2f(wb, pb1, dot2f(wa, pb0, b2f[o]))));
                x2a[o] = fmaxf(s0, 0.f);
                x2b[o] = fmaxf(s1, 0.f);
            }
            h2 qa0 = __builtin_amdgcn_cvt_pkrtz(x2a[0], x2a[1]);
            h2 qa1 = __builtin_amdgcn_cvt_pkrtz(x2a[2], x2a[3]);
            h2 qa2 = __builtin_amdgcn_cvt_pkrtz(x2a[4], x2a[5]);
            h2 qa3 = __builtin_amdgcn_cvt_pkrtz(x2a[6], x2a[7]);
            h2 qb0 = __builtin_amdgcn_cvt_pkrtz(x2b[0], x2b[1]);
            h2 qb1 = __builtin_amdgcn_cvt_pkrtz(x2b[2], x2b[3]);
            h2 qb2 = __builtin_amdgcn_cvt_pkrtz(x2b[4], x2b[5]);
            h2 qb3 = __builtin_amdgcn_cvt_pkrtz(x2b[6], x2b[7]);

            h2 w3a = __builtin_bit_cast(h2, w3r.x), w3b = __builtin_bit_cast(h2, w3r.y),
               w3c = __builtin_bit_cast(h2, w3r.z), w3d = __builtin_bit_cast(h2, w3r.w);
            float lg0 = dot2f(w3d, qa3, dot2f(w3c, qa2, dot2f(w3b, qa1, dot2f(w3a, qa0, b3v))));
            float lg1 = dot2f(w3d, qb3, dot2f(w3c, qb2, dot2f(w3b, qb1, dot2f(w3a, qb0, b3v))));
            *(float2*)(cp + 2 * q) = make_float2(lg0, lg1);
        }
    }
}

// ---------------- launch ----------------
extern "C" void kernel_launch(void* const* d_in, const int* in_sizes, int n_in,
                              void* d_out, int out_size, void* d_ws, size_t ws_size,
                              hipStream_t stream) {
    const float* dec4         = (const float*)d_in[0];
    const float* feat         = (const float*)d_in[1];
    const float* gn_pre_gamma = (const float*)d_in[2];
    const float* gn_pre_beta  = (const float*)d_in[3];
    const float* W_pre        = (const float*)d_in[4];
    const float* b_pre        = (const float*)d_in[5];
    const float* gn_gap_gamma = (const float*)d_in[6];
    const float* gn_gap_beta  = (const float*)d_in[7];
    const float* W_gap        = (const float*)d_in[8];
    const float* b_gap        = (const float*)d_in[9];
    const float* emb          = (const float*)d_in[10];
    const float* W_ctrl       = (const float*)d_in[11];
    const float* b_ctrl       = (const float*)d_in[12];
    float* out = (float*)d_out;
    float* ws  = (float*)d_ws;

    float* partials = ws;            // 2048 floats
    float* g_buf    = ws + 2048;     // 2048
    float* E_buf    = ws + 4096;     // 4896
    float* pkParams = ws + 8992;     // 10240 floats (40960 B, 16B-aligned)

    prep<<<1120, 256, 0, stream>>>(feat, dec4, gn_gap_gamma, gn_gap_beta,
                                   emb, W_ctrl, partials, g_buf, E_buf);
    fc<<<4, 256, 0, stream>>>(g_buf, W_gap, b_gap, W_ctrl, b_ctrl, E_buf,
                              (unsigned char*)pkParams);
    main_fused<<<512, 256, 0, stream>>>(feat, partials, gn_pre_gamma, gn_pre_beta,
                                        W_pre, b_pre, (const float4*)pkParams, out);
}